// Round 9
// baseline (190.849 us; speedup 1.0000x reference)
//
#include <hip/hip_runtime.h>
#include <math.h>

constexpr int SEQ  = 2048;
constexpr int HID  = 1024;
constexpr int MTOT = 4096;     // B*S
constexpr int BH   = 32;       // B*nh

typedef _Float16 f16;
typedef _Float16 f16x8 __attribute__((ext_vector_type(8)));
typedef float    f32x4 __attribute__((ext_vector_type(4)));

// ---------------------------------------------------------------------------
// prep: z=0: Wq-Wk -> WqkT, z=1: Wv -> WvT, z=2: Wo -> WoT  (transpose+f16)
//       z=3: x fp32 -> f16 flat copy
// ---------------------------------------------------------------------------
__global__ __launch_bounds__(256) void prep(const float* __restrict__ x,
                                            const float* __restrict__ Wq,
                                            const float* __restrict__ Wk,
                                            const float* __restrict__ Wv,
                                            const float* __restrict__ Wo,
                                            f16* __restrict__ xh,
                                            f16* __restrict__ WqkT,
                                            f16* __restrict__ WvT,
                                            f16* __restrict__ WoT) {
    __shared__ f16 T[64][72];
    const int z = blockIdx.z;
    const int t = threadIdx.x;

    if (z == 3) {   // x convert: 256 chunks of 16384 elems
        const int chunk = blockIdx.y * 16 + blockIdx.x;
        const float* src = x + (size_t)chunk * 16384;
        f16* dst = xh + (size_t)chunk * 16384;
#pragma unroll
        for (int it = 0; it < 16; it++) {
            const int i = it * 1024 + t * 4;
            float4 v = *(const float4*)(src + i);
            f16 o[4] = {(f16)v.x, (f16)v.y, (f16)v.z, (f16)v.w};
            *(ushort4*)(dst + i) = *(ushort4*)o;
        }
        return;
    }

    const float* W  = (z == 0) ? Wq : (z == 1) ? Wv : Wo;
    f16* WT = (z == 0) ? WqkT : (z == 1) ? WvT : WoT;
    const int k0 = blockIdx.x * 64, n0 = blockIdx.y * 64;
    const int r  = t >> 4;
    const int c4 = (t & 15) * 4;
#pragma unroll
    for (int rr = 0; rr < 64; rr += 16) {
        float4 w = *(const float4*)(W + (size_t)(k0 + rr + r) * HID + n0 + c4);
        if (z == 0) {
            float4 w2 = *(const float4*)(Wk + (size_t)(k0 + rr + r) * HID + n0 + c4);
            w.x -= w2.x; w.y -= w2.y; w.z -= w2.z; w.w -= w2.w;
        }
        T[c4 + 0][rr + r] = (f16)w.x;
        T[c4 + 1][rr + r] = (f16)w.y;
        T[c4 + 2][rr + r] = (f16)w.z;
        T[c4 + 3][rr + r] = (f16)w.w;
    }
    __syncthreads();
#pragma unroll
    for (int pp = 0; pp < 2; pp++) {
        const int nr = pp * 32 + (t >> 3);
        const int kc = (t & 7) * 8;
        *(uint4*)(WT + (size_t)(n0 + nr) * HID + k0 + kc) = *(uint4*)(&T[nr][kc]);
    }
}

// ---------------------------------------------------------------------------
// Fused projection GEMM (dif + vT): 128x64 tile, single-buffer LDS 27.6 KB,
// grid 32x32 = 1024 blocks = 4/CU. N=2048 virtual (first 1024->dif, rest->vT).
// ---------------------------------------------------------------------------
__global__ __launch_bounds__(256, 4) void proj_gemm(const f16* __restrict__ A,
                                                    const f16* __restrict__ WqkT,
                                                    const f16* __restrict__ WvT,
                                                    const float* __restrict__ bq,
                                                    const float* __restrict__ bk,
                                                    const float* __restrict__ bv,
                                                    f16* __restrict__ dif,
                                                    f16* __restrict__ vT) {
    __shared__ f16 As[128 * 72];
    __shared__ f16 Bs[64 * 72];
    const int t = threadIdx.x;
    const int m0  = blockIdx.x * 128;
    const int n0g = blockIdx.y * 64;
    const bool isv = (n0g >= HID);
    const f16* BT = isv ? WvT : WqkT;
    const int n0 = n0g & (HID - 1);
    const int w = t >> 6, l = t & 63, quad = l >> 4, ln = l & 15;
    const int wm = w * 32;
    const int arow = t >> 1, ahalf = (t & 1) * 32;
    const int brow = t >> 2, boff = (t & 3) * 16;

    const f16* pa = A  + (size_t)(m0 + arow) * HID + ahalf;
    const f16* pb = BT + (size_t)(n0 + brow) * HID + boff;

    uint4 ar0 = *(const uint4*)(pa),      ar1 = *(const uint4*)(pa + 8);
    uint4 ar2 = *(const uint4*)(pa + 16), ar3 = *(const uint4*)(pa + 24);
    uint4 br0 = *(const uint4*)(pb),      br1 = *(const uint4*)(pb + 8);

    f32x4 acc[2][4] = {};

    for (int k0 = 0; k0 < HID; k0 += 64) {
        __syncthreads();   // prior iter frag reads done
        f16* da = As + arow * 72 + ahalf;
        *(uint4*)(da)      = ar0; *(uint4*)(da + 8)  = ar1;
        *(uint4*)(da + 16) = ar2; *(uint4*)(da + 24) = ar3;
        f16* db = Bs + brow * 72 + boff;
        *(uint4*)(db) = br0; *(uint4*)(db + 8) = br1;
        __syncthreads();
        if (k0 + 64 < HID) {   // prefetch next slab while MFMAs run
            const f16* qa = pa + k0 + 64;
            const f16* qb = pb + k0 + 64;
            ar0 = *(const uint4*)(qa);      ar1 = *(const uint4*)(qa + 8);
            ar2 = *(const uint4*)(qa + 16); ar3 = *(const uint4*)(qa + 24);
            br0 = *(const uint4*)(qb);      br1 = *(const uint4*)(qb + 8);
        }
#pragma unroll
        for (int kh = 0; kh < 2; kh++) {
            f16x8 af[2], bf[4];
#pragma unroll
            for (int mt = 0; mt < 2; mt++)
                af[mt] = *(const f16x8*)(As + (wm + mt * 16 + ln) * 72 + kh * 32 + quad * 8);
#pragma unroll
            for (int nt = 0; nt < 4; nt++)
                bf[nt] = *(const f16x8*)(Bs + (nt * 16 + ln) * 72 + kh * 32 + quad * 8);
#pragma unroll
            for (int mt = 0; mt < 2; mt++)
#pragma unroll
                for (int nt = 0; nt < 4; nt++)
                    acc[mt][nt] = __builtin_amdgcn_mfma_f32_16x16x32_f16(
                        af[mt], bf[nt], acc[mt][nt], 0, 0, 0);
        }
    }

#pragma unroll
    for (int mt = 0; mt < 2; mt++) {
#pragma unroll
        for (int nt = 0; nt < 4; nt++) {
            const int nl = n0 + nt * 16 + ln;
            const int m_base = m0 + wm + mt * 16 + quad * 4;
            const int h = nl >> 6, e = nl & 63;
            if (!isv) {
                const float bb = bq[nl] - bk[nl];
#pragma unroll
                for (int r = 0; r < 4; r++) {
                    const int m = m_base + r;
                    const int b = m >> 11, s = m & 2047;
                    dif[((size_t)(b * 16 + h) * SEQ + s) * 64 + e] =
                        (f16)(acc[mt][nt][r] + bb);
                }
            } else {
                const float bb = bv[nl];
                const int b = m_base >> 11, s0 = m_base & 2047;
                f16 o[4];
#pragma unroll
                for (int r = 0; r < 4; r++) o[r] = (f16)(acc[mt][nt][r] + bb);
                *(ushort4*)(&vT[((size_t)(b * 16 + h) * 64 + e) * SEQ + s0]) =
                    *(ushort4*)o;
            }
        }
    }
}

// ---------------------------------------------------------------------------
// Output GEMM: out = (C0+C1) @ WoT^T * 65536 + bo. 128x64 tile, dbuf LDS.
// ---------------------------------------------------------------------------
__global__ __launch_bounds__(256) void out_gemm(const f16* __restrict__ C0,
                                                const f16* __restrict__ C1,
                                                const f16* __restrict__ WoT,
                                                const float* __restrict__ bo,
                                                float* __restrict__ out) {
    __shared__ f16 As[2][128 * 72];
    __shared__ f16 Bs[2][64 * 72];
    const int t = threadIdx.x;
    const int m0 = blockIdx.x * 128, n0 = blockIdx.y * 64;
    const int w = t >> 6, l = t & 63, quad = l >> 4, ln = l & 15;
    const int wm = (w >> 1) * 64, wn = (w & 1) * 32;
    const int arow = t >> 1, ahalf = (t & 1) * 32;
    const int brow = t >> 2, boff = (t & 3) * 16;

    const f16* pa0 = C0  + (size_t)(m0 + arow) * HID + ahalf;
    const f16* pa1 = C1  + (size_t)(m0 + arow) * HID + ahalf;
    const f16* pb  = WoT + (size_t)(n0 + brow) * HID + boff;

    f16x8 a0 = *(const f16x8*)(pa0)      + *(const f16x8*)(pa1);
    f16x8 a1 = *(const f16x8*)(pa0 + 8)  + *(const f16x8*)(pa1 + 8);
    f16x8 a2 = *(const f16x8*)(pa0 + 16) + *(const f16x8*)(pa1 + 16);
    f16x8 a3 = *(const f16x8*)(pa0 + 24) + *(const f16x8*)(pa1 + 24);
    uint4 b0 = *(const uint4*)(pb), b1 = *(const uint4*)(pb + 8);

    f32x4 acc[4][2] = {};
    int buf = 0;

    for (int k0 = 0; k0 < HID; k0 += 64) {
        f16* da = As[buf] + arow * 72 + ahalf;
        *(f16x8*)(da)      = a0; *(f16x8*)(da + 8)  = a1;
        *(f16x8*)(da + 16) = a2; *(f16x8*)(da + 24) = a3;
        f16* db = Bs[buf] + brow * 72 + boff;
        *(uint4*)(db) = b0; *(uint4*)(db + 8) = b1;
        __syncthreads();
        if (k0 + 64 < HID) {
            const int kn = k0 + 64;
            a0 = *(const f16x8*)(pa0 + kn)      + *(const f16x8*)(pa1 + kn);
            a1 = *(const f16x8*)(pa0 + kn + 8)  + *(const f16x8*)(pa1 + kn + 8);
            a2 = *(const f16x8*)(pa0 + kn + 16) + *(const f16x8*)(pa1 + kn + 16);
            a3 = *(const f16x8*)(pa0 + kn + 24) + *(const f16x8*)(pa1 + kn + 24);
            b0 = *(const uint4*)(pb + kn); b1 = *(const uint4*)(pb + kn + 8);
        }
#pragma unroll
        for (int kh = 0; kh < 2; kh++) {
            f16x8 af[4], bf[2];
#pragma unroll
            for (int mt = 0; mt < 4; mt++)
                af[mt] = *(const f16x8*)(As[buf] + (wm + mt * 16 + ln) * 72 + kh * 32 + quad * 8);
#pragma unroll
            for (int nt = 0; nt < 2; nt++)
                bf[nt] = *(const f16x8*)(Bs[buf] + (wn + nt * 16 + ln) * 72 + kh * 32 + quad * 8);
#pragma unroll
            for (int mt = 0; mt < 4; mt++)
#pragma unroll
                for (int nt = 0; nt < 2; nt++)
                    acc[mt][nt] = __builtin_amdgcn_mfma_f32_16x16x32_f16(
                        af[mt], bf[nt], acc[mt][nt], 0, 0, 0);
        }
        buf ^= 1;
    }

#pragma unroll
    for (int mt = 0; mt < 4; mt++)
#pragma unroll
        for (int nt = 0; nt < 2; nt++) {
            const int n = n0 + wn + nt * 16 + ln;
            const float bb = bo[n];
            const int m_base = m0 + wm + mt * 16 + quad * 4;
#pragma unroll
            for (int r = 0; r < 4; r++)
                out[(size_t)(m_base + r) * HID + n] =
                    acc[mt][nt][r] * 65536.0f + bb;
        }
}

// ---------------------------------------------------------------------------
// fp16 MFMA attention (R6 structure): k-split x2, grid 16x32x2 = 1024 blocks.
// R9: Q frags hoisted to registers (loop-invariant); 2^-16 folded into exp arg.
// ---------------------------------------------------------------------------
__global__ __launch_bounds__(256) void attn_f16(const f16* __restrict__ dif,
                                                const f16* __restrict__ vT,
                                                f16* __restrict__ ctx0,
                                                f16* __restrict__ ctx1) {
    __shared__ f16 Qs[64 * 72];
    __shared__ f16 Ks[64 * 72];
    __shared__ f16 Vs[64 * 72];
    __shared__ f16 Ps[64 * 72];

    const int pq = blockIdx.x, bh = blockIdx.y, ks = blockIdx.z;
    f16* Cout = ks ? ctx1 : ctx0;
    const f16* D  = dif + (size_t)bh * SEQ * 64;
    const f16* VT = vT  + (size_t)bh * 64 * SEQ;
    const int b = bh >> 4, h = bh & 15;
    const int t = threadIdx.x, w = t >> 6, l = t & 63, quad = l >> 4, ln = l & 15;
    const int ve = t >> 2, vc = (t & 3) * 16;

    for (int half = 0; half < 2; half++) {
        const int qt = half ? (31 - pq) : pq;
        const int i0 = qt * 64;
        __syncthreads();   // prior half's LDS reads complete

        // stage Q, then pull the loop-invariant A-frags into registers
#pragma unroll
        for (int rr = 0; rr < 2; rr++) {
            const int o = rr * 2048 + t * 8;
            uint4 v = *(const uint4*)(D + i0 * 64 + o);
            *(uint4*)(Qs + (o >> 6) * 72 + (o & 63)) = v;
        }
        __syncthreads();
        f16x8 aq[2];
#pragma unroll
        for (int kh = 0; kh < 2; kh++)
            aq[kh] = *(const f16x8*)(Qs + (w * 16 + ln) * 72 + kh * 32 + quad * 8);

        f32x4 acc[4] = {};
        const int kt0 = qt + ks;

        uint4 kr0, kr1, vr0, vr1;
        if (kt0 < 32) {
            const int j0 = kt0 * 64;
            kr0 = *(const uint4*)(D + j0 * 64 + t * 8);
            kr1 = *(const uint4*)(D + j0 * 64 + 2048 + t * 8);
            vr0 = *(const uint4*)(VT + (size_t)ve * SEQ + j0 + vc);
            vr1 = *(const uint4*)(VT + (size_t)ve * SEQ + j0 + vc + 8);
        }

        for (int kt = kt0; kt < 32; kt += 2) {
            __syncthreads();   // prev iter frag reads done

            {
                const int o0 = t * 8, o1 = 2048 + t * 8;
                *(uint4*)(Ks + (o0 >> 6) * 72 + (o0 & 63)) = kr0;
                *(uint4*)(Ks + (o1 >> 6) * 72 + (o1 & 63)) = kr1;
                *(uint4*)(Vs + ve * 72 + vc)     = vr0;
                *(uint4*)(Vs + ve * 72 + vc + 8) = vr1;
            }
            __syncthreads();

            if (kt + 2 < 32) {
                const int j2 = (kt + 2) * 64;
                kr0 = *(const uint4*)(D + j2 * 64 + t * 8);
                kr1 = *(const uint4*)(D + j2 * 64 + 2048 + t * 8);
                vr0 = *(const uint4*)(VT + (size_t)ve * SEQ + j2 + vc);
                vr1 = *(const uint4*)(VT + (size_t)ve * SEQ + j2 + vc + 8);
            }

            // S = Q . K^T
            f32x4 s[4] = {};
#pragma unroll
            for (int kh = 0; kh < 2; kh++)
#pragma unroll
                for (int nt = 0; nt < 4; nt++) {
                    f16x8 bfr = *(const f16x8*)(Ks + (nt * 16 + ln) * 72 + kh * 32 + quad * 8);
                    s[nt] = __builtin_amdgcn_mfma_f32_16x16x32_f16(aq[kh], bfr, s[nt], 0, 0, 0);
                }

            // P = mask * exp(-0.5*s - 16*ln2)   (2^-16 pre-scale folded in)
            const bool full = (kt > qt);
#pragma unroll
            for (int nt = 0; nt < 4; nt++)
#pragma unroll
                for (int r = 0; r < 4; r++) {
                    const int iloc = w * 16 + quad * 4 + r;
                    const int jloc = nt * 16 + ln;
                    float p = (full || (jloc > iloc))
                                  ? fminf(__expf(fmaf(s[nt][r], -0.5f,
                                                      -11.090354888959125f)), 60000.0f)
                                  : 0.0f;
                    Ps[iloc * 72 + jloc] = (f16)p;
                }

            // ctx += P @ V
#pragma unroll
            for (int kh = 0; kh < 2; kh++) {
                f16x8 a = *(const f16x8*)(Ps + (w * 16 + ln) * 72 + kh * 32 + quad * 8);
#pragma unroll
                for (int nt = 0; nt < 4; nt++) {
                    f16x8 bfr = *(const f16x8*)(Vs + (nt * 16 + ln) * 72 + kh * 32 + quad * 8);
                    acc[nt] = __builtin_amdgcn_mfma_f32_16x16x32_f16(a, bfr, acc[nt], 0, 0, 0);
                }
            }
        }

#pragma unroll
        for (int nt = 0; nt < 4; nt++)
#pragma unroll
            for (int r = 0; r < 4; r++) {
                const int iloc = w * 16 + quad * 4 + r;
                Cout[(size_t)(b * SEQ + i0 + iloc) * HID + h * 64 + nt * 16 + ln] =
                    (f16)acc[nt][r];
            }
    }
}

// ---------------------------------------------------------------------------
extern "C" void kernel_launch(void* const* d_in, const int* in_sizes, int n_in,
                              void* d_out, int out_size, void* d_ws, size_t ws_size,
                              hipStream_t stream) {
    const float* x  = (const float*)d_in[0];
    const float* Wq = (const float*)d_in[1];
    const float* bq = (const float*)d_in[2];
    const float* Wk = (const float*)d_in[3];
    const float* bk = (const float*)d_in[4];
    const float* Wv = (const float*)d_in[5];
    const float* bv = (const float*)d_in[6];
    const float* Wo = (const float*)d_in[7];
    const float* bo = (const float*)d_in[8];
    float* out = (float*)d_out;

    char* ws = (char*)d_ws;
    f16* xh   = (f16*)(ws);               // 8 MB  [M][1024]
    f16* WqkT = (f16*)(ws + (8 << 20));   // 2 MB  [n][k]
    f16* WvT  = (f16*)(ws + (10 << 20));  // 2 MB
    f16* WoT  = (f16*)(ws + (12 << 20));  // 2 MB
    f16* dif  = (f16*)(ws + (14 << 20));  // 8 MB  [bh][s][64]
    f16* vT   = (f16*)(ws + (22 << 20));  // 8 MB  [bh][e][s]
    f16* ctx0 = (f16*)(ws + (30 << 20));  // 8 MB  partial (x 2^-16)
    f16* ctx1 = (f16*)(ws + (38 << 20));  // 8 MB  partial

    prep<<<dim3(16, 16, 4), 256, 0, stream>>>(x, Wq, Wk, Wv, Wo,
                                              xh, WqkT, WvT, WoT);
    proj_gemm<<<dim3(MTOT / 128, 32), 256, 0, stream>>>(xh, WqkT, WvT,
                                                        bq, bk, bv, dif, vT);
    attn_f16<<<dim3(16, BH, 2), 256, 0, stream>>>(dif, vT, ctx0, ctx1);
    out_gemm<<<dim3(MTOT / 128, 16), 256, 0, stream>>>(ctx0, ctx1, WoT, bo, out);
}

// Round 10
// 186.652 us; speedup vs baseline: 1.0225x; 1.0225x over previous
//
#include <hip/hip_runtime.h>
#include <math.h>

constexpr int SEQ  = 2048;
constexpr int HID  = 1024;
constexpr int MTOT = 4096;     // B*S
constexpr int BH   = 32;       // B*nh

typedef _Float16 f16;
typedef _Float16 f16x8 __attribute__((ext_vector_type(8)));
typedef float    f32x4 __attribute__((ext_vector_type(4)));

// async global->LDS, 16B per lane; lds dest = wave-uniform base + lane*16
__device__ __forceinline__ void gld16(const f16* g, f16* l) {
    __builtin_amdgcn_global_load_lds(
        (__attribute__((address_space(1))) void*)g,
        (__attribute__((address_space(3))) void*)l, 16, 0, 0);
}

// ---------------------------------------------------------------------------
// prep: z=0: Wq-Wk -> WqkT, z=1: Wv -> WvT, z=2: Wo -> WoT  (transpose+f16)
//       z=3: x fp32 -> f16 flat copy
// ---------------------------------------------------------------------------
__global__ __launch_bounds__(256) void prep(const float* __restrict__ x,
                                            const float* __restrict__ Wq,
                                            const float* __restrict__ Wk,
                                            const float* __restrict__ Wv,
                                            const float* __restrict__ Wo,
                                            f16* __restrict__ xh,
                                            f16* __restrict__ WqkT,
                                            f16* __restrict__ WvT,
                                            f16* __restrict__ WoT) {
    __shared__ f16 T[64][72];
    const int z = blockIdx.z;
    const int t = threadIdx.x;

    if (z == 3) {
        const int chunk = blockIdx.y * 16 + blockIdx.x;
        const float* src = x + (size_t)chunk * 16384;
        f16* dst = xh + (size_t)chunk * 16384;
#pragma unroll
        for (int it = 0; it < 16; it++) {
            const int i = it * 1024 + t * 4;
            float4 v = *(const float4*)(src + i);
            f16 o[4] = {(f16)v.x, (f16)v.y, (f16)v.z, (f16)v.w};
            *(ushort4*)(dst + i) = *(ushort4*)o;
        }
        return;
    }

    const float* W  = (z == 0) ? Wq : (z == 1) ? Wv : Wo;
    f16* WT = (z == 0) ? WqkT : (z == 1) ? WvT : WoT;
    const int k0 = blockIdx.x * 64, n0 = blockIdx.y * 64;
    const int r  = t >> 4;
    const int c4 = (t & 15) * 4;
#pragma unroll
    for (int rr = 0; rr < 64; rr += 16) {
        float4 w = *(const float4*)(W + (size_t)(k0 + rr + r) * HID + n0 + c4);
        if (z == 0) {
            float4 w2 = *(const float4*)(Wk + (size_t)(k0 + rr + r) * HID + n0 + c4);
            w.x -= w2.x; w.y -= w2.y; w.z -= w2.z; w.w -= w2.w;
        }
        T[c4 + 0][rr + r] = (f16)w.x;
        T[c4 + 1][rr + r] = (f16)w.y;
        T[c4 + 2][rr + r] = (f16)w.z;
        T[c4 + 3][rr + r] = (f16)w.w;
    }
    __syncthreads();
#pragma unroll
    for (int pp = 0; pp < 2; pp++) {
        const int nr = pp * 32 + (t >> 3);
        const int kc = (t & 7) * 8;
        *(uint4*)(WT + (size_t)(n0 + nr) * HID + k0 + kc) = *(uint4*)(&T[nr][kc]);
    }
}

// ---------------------------------------------------------------------------
// Fused projection GEMM (dif + vT): 128x64 tile, global_load_lds staging with
// XOR-octet swizzle (LDS[row][o] = G[row][o ^ (row&7)], pitch 64, no pad).
// Epilogues bounce through LDS for coalesced 16B stores.
// Grid 32x32 = 1024 blocks. N=2048 virtual (first 1024->dif, rest->vT).
// ---------------------------------------------------------------------------
__global__ __launch_bounds__(256, 4) void proj_gemm(const f16* __restrict__ A,
                                                    const f16* __restrict__ WqkT,
                                                    const f16* __restrict__ WvT,
                                                    const float* __restrict__ bq,
                                                    const float* __restrict__ bk,
                                                    const float* __restrict__ bv,
                                                    f16* __restrict__ dif,
                                                    f16* __restrict__ vT) {
    __shared__ f16 As[128 * 72];   // staging uses pitch 64 (16 KB); epilogue reuses
    __shared__ f16 Bs[64 * 64];
    const int t = threadIdx.x;
    const int m0  = blockIdx.x * 128;
    const int n0g = blockIdx.y * 64;
    const bool isv = (n0g >= HID);
    const f16* BT = isv ? WvT : WqkT;
    const int n0 = n0g & (HID - 1);
    const int w = t >> 6, l = t & 63, quad = l >> 4, ln = l & 15;
    const int wm = w * 32;
    const int xk = ln & 7;               // frag-read xor key (= row&7)

    // staging lane decode: chunk = 8 rows x 64k; lane l -> row l>>3, oct-slot l&7
    const int srow8 = l >> 3;
    const int soct  = (l & 7) ^ srow8;   // global octet this lane fetches
    const f16* pa = A  + (size_t)(m0 + w * 32 + srow8) * HID + soct * 8;
    const f16* pb = BT + (size_t)(n0 + w * 16 + srow8) * HID + soct * 8;

    f32x4 acc[2][4] = {};

    for (int k0 = 0; k0 < HID; k0 += 64) {
        __syncthreads();                 // prev iter frag reads done
#pragma unroll
        for (int c = 0; c < 4; c++)
            gld16(pa + (size_t)c * 8 * HID + k0, As + (w * 4 + c) * 512);
#pragma unroll
        for (int c = 0; c < 2; c++)
            gld16(pb + (size_t)c * 8 * HID + k0, Bs + (w * 2 + c) * 512);
        __syncthreads();                 // drains vmcnt, data visible

#pragma unroll
        for (int kh = 0; kh < 2; kh++) {
            f16x8 af[2], bf[4];
#pragma unroll
            for (int mt = 0; mt < 2; mt++) {
                const int row = wm + mt * 16 + ln;
                const int oct = (kh * 4 + quad) ^ xk;
                af[mt] = *(const f16x8*)(As + row * 64 + oct * 8);
            }
#pragma unroll
            for (int nt = 0; nt < 4; nt++) {
                const int row = nt * 16 + ln;
                const int oct = (kh * 4 + quad) ^ xk;
                bf[nt] = *(const f16x8*)(Bs + row * 64 + oct * 8);
            }
#pragma unroll
            for (int mt = 0; mt < 2; mt++)
#pragma unroll
                for (int nt = 0; nt < 4; nt++)
                    acc[mt][nt] = __builtin_amdgcn_mfma_f32_16x16x32_f16(
                        af[mt], bf[nt], acc[mt][nt], 0, 0, 0);
        }
    }

    // ---- epilogue via LDS bounce (coalesced 16B global stores) ----
    __syncthreads();                     // last frag reads done, As reusable
    const int b_  = m0 >> 11;
    const int s0g = m0 & 2047;
    const int h_  = n0 >> 6;

    if (!isv) {                          // dif: [s 128][e 64], LDS pitch 72
        float bb[4];
#pragma unroll
        for (int nt = 0; nt < 4; nt++) {
            const int nl = n0 + nt * 16 + ln;
            bb[nt] = bq[nl] - bk[nl];
        }
#pragma unroll
        for (int mt = 0; mt < 2; mt++)
#pragma unroll
            for (int nt = 0; nt < 4; nt++)
#pragma unroll
                for (int r = 0; r < 4; r++) {
                    const int sl = wm + mt * 16 + quad * 4 + r;
                    As[sl * 72 + nt * 16 + ln] = (f16)(acc[mt][nt][r] + bb[nt]);
                }
        __syncthreads();
        f16* base = dif + ((size_t)(b_ * 16 + h_) * SEQ + s0g) * 64;
        const int sl = t >> 1, eo = (t & 1) * 32;
#pragma unroll
        for (int i = 0; i < 4; i++)
            *(uint4*)(base + (size_t)sl * 64 + eo + i * 8) =
                *(uint4*)(&As[sl * 72 + eo + i * 8]);
    } else {                             // vT: [e 64][s 128], LDS pitch 136
        float bb[4];
#pragma unroll
        for (int nt = 0; nt < 4; nt++)
            bb[nt] = bv[n0 + nt * 16 + ln];
#pragma unroll
        for (int mt = 0; mt < 2; mt++)
#pragma unroll
            for (int nt = 0; nt < 4; nt++)
#pragma unroll
                for (int r = 0; r < 4; r++) {
                    const int sl = wm + mt * 16 + quad * 4 + r;
                    As[(nt * 16 + ln) * 136 + sl] = (f16)(acc[mt][nt][r] + bb[nt]);
                }
        __syncthreads();
        const int eb = t >> 2, so = (t & 3) * 32;
        f16* base = vT + ((size_t)(b_ * 16 + h_) * 64 + eb) * SEQ + s0g + so;
#pragma unroll
        for (int i = 0; i < 4; i++)
            *(uint4*)(base + i * 8) = *(uint4*)(&As[eb * 136 + so + i * 8]);
    }
}

// ---------------------------------------------------------------------------
// Output GEMM: out = (C0+C1) @ WoT^T * 65536 + bo. 128x64 tile, dbuf LDS.
// ---------------------------------------------------------------------------
__global__ __launch_bounds__(256) void out_gemm(const f16* __restrict__ C0,
                                                const f16* __restrict__ C1,
                                                const f16* __restrict__ WoT,
                                                const float* __restrict__ bo,
                                                float* __restrict__ out) {
    __shared__ f16 As[2][128 * 72];
    __shared__ f16 Bs[2][64 * 72];
    const int t = threadIdx.x;
    const int m0 = blockIdx.x * 128, n0 = blockIdx.y * 64;
    const int w = t >> 6, l = t & 63, quad = l >> 4, ln = l & 15;
    const int wm = (w >> 1) * 64, wn = (w & 1) * 32;
    const int arow = t >> 1, ahalf = (t & 1) * 32;
    const int brow = t >> 2, boff = (t & 3) * 16;

    const f16* pa0 = C0  + (size_t)(m0 + arow) * HID + ahalf;
    const f16* pa1 = C1  + (size_t)(m0 + arow) * HID + ahalf;
    const f16* pb  = WoT + (size_t)(n0 + brow) * HID + boff;

    f16x8 a0 = *(const f16x8*)(pa0)      + *(const f16x8*)(pa1);
    f16x8 a1 = *(const f16x8*)(pa0 + 8)  + *(const f16x8*)(pa1 + 8);
    f16x8 a2 = *(const f16x8*)(pa0 + 16) + *(const f16x8*)(pa1 + 16);
    f16x8 a3 = *(const f16x8*)(pa0 + 24) + *(const f16x8*)(pa1 + 24);
    uint4 b0 = *(const uint4*)(pb), b1 = *(const uint4*)(pb + 8);

    f32x4 acc[4][2] = {};
    int buf = 0;

    for (int k0 = 0; k0 < HID; k0 += 64) {
        f16* da = As[buf] + arow * 72 + ahalf;
        *(f16x8*)(da)      = a0; *(f16x8*)(da + 8)  = a1;
        *(f16x8*)(da + 16) = a2; *(f16x8*)(da + 24) = a3;
        f16* db = Bs[buf] + brow * 72 + boff;
        *(uint4*)(db) = b0; *(uint4*)(db + 8) = b1;
        __syncthreads();
        if (k0 + 64 < HID) {
            const int kn = k0 + 64;
            a0 = *(const f16x8*)(pa0 + kn)      + *(const f16x8*)(pa1 + kn);
            a1 = *(const f16x8*)(pa0 + kn + 8)  + *(const f16x8*)(pa1 + kn + 8);
            a2 = *(const f16x8*)(pa0 + kn + 16) + *(const f16x8*)(pa1 + kn + 16);
            a3 = *(const f16x8*)(pa0 + kn + 24) + *(const f16x8*)(pa1 + kn + 24);
            b0 = *(const uint4*)(pb + kn); b1 = *(const uint4*)(pb + kn + 8);
        }
#pragma unroll
        for (int kh = 0; kh < 2; kh++) {
            f16x8 af[4], bf[2];
#pragma unroll
            for (int mt = 0; mt < 4; mt++)
                af[mt] = *(const f16x8*)(As[buf] + (wm + mt * 16 + ln) * 72 + kh * 32 + quad * 8);
#pragma unroll
            for (int nt = 0; nt < 2; nt++)
                bf[nt] = *(const f16x8*)(Bs[buf] + (wn + nt * 16 + ln) * 72 + kh * 32 + quad * 8);
#pragma unroll
            for (int mt = 0; mt < 4; mt++)
#pragma unroll
                for (int nt = 0; nt < 2; nt++)
                    acc[mt][nt] = __builtin_amdgcn_mfma_f32_16x16x32_f16(
                        af[mt], bf[nt], acc[mt][nt], 0, 0, 0);
        }
        buf ^= 1;
    }

#pragma unroll
    for (int mt = 0; mt < 4; mt++)
#pragma unroll
        for (int nt = 0; nt < 2; nt++) {
            const int n = n0 + wn + nt * 16 + ln;
            const float bb = bo[n];
            const int m_base = m0 + wm + mt * 16 + quad * 4;
#pragma unroll
            for (int r = 0; r < 4; r++)
                out[(size_t)(m_base + r) * HID + n] =
                    acc[mt][nt][r] * 65536.0f + bb;
        }
}

// ---------------------------------------------------------------------------
// fp16 MFMA attention (R9 known-good): k-split x2, grid 16x32x2 = 1024 blocks,
// Q frags hoisted to registers, 2^-16 folded into exp argument.
// ---------------------------------------------------------------------------
__global__ __launch_bounds__(256) void attn_f16(const f16* __restrict__ dif,
                                                const f16* __restrict__ vT,
                                                f16* __restrict__ ctx0,
                                                f16* __restrict__ ctx1) {
    __shared__ f16 Qs[64 * 72];
    __shared__ f16 Ks[64 * 72];
    __shared__ f16 Vs[64 * 72];
    __shared__ f16 Ps[64 * 72];

    const int pq = blockIdx.x, bh = blockIdx.y, ks = blockIdx.z;
    f16* Cout = ks ? ctx1 : ctx0;
    const f16* D  = dif + (size_t)bh * SEQ * 64;
    const f16* VT = vT  + (size_t)bh * 64 * SEQ;
    const int b = bh >> 4, h = bh & 15;
    const int t = threadIdx.x, w = t >> 6, l = t & 63, quad = l >> 4, ln = l & 15;
    const int ve = t >> 2, vc = (t & 3) * 16;

    for (int half = 0; half < 2; half++) {
        const int qt = half ? (31 - pq) : pq;
        const int i0 = qt * 64;
        __syncthreads();

#pragma unroll
        for (int rr = 0; rr < 2; rr++) {
            const int o = rr * 2048 + t * 8;
            uint4 v = *(const uint4*)(D + i0 * 64 + o);
            *(uint4*)(Qs + (o >> 6) * 72 + (o & 63)) = v;
        }
        __syncthreads();
        f16x8 aq[2];
#pragma unroll
        for (int kh = 0; kh < 2; kh++)
            aq[kh] = *(const f16x8*)(Qs + (w * 16 + ln) * 72 + kh * 32 + quad * 8);

        f32x4 acc[4] = {};
        const int kt0 = qt + ks;

        uint4 kr0, kr1, vr0, vr1;
        if (kt0 < 32) {
            const int j0 = kt0 * 64;
            kr0 = *(const uint4*)(D + j0 * 64 + t * 8);
            kr1 = *(const uint4*)(D + j0 * 64 + 2048 + t * 8);
            vr0 = *(const uint4*)(VT + (size_t)ve * SEQ + j0 + vc);
            vr1 = *(const uint4*)(VT + (size_t)ve * SEQ + j0 + vc + 8);
        }

        for (int kt = kt0; kt < 32; kt += 2) {
            __syncthreads();

            {
                const int o0 = t * 8, o1 = 2048 + t * 8;
                *(uint4*)(Ks + (o0 >> 6) * 72 + (o0 & 63)) = kr0;
                *(uint4*)(Ks + (o1 >> 6) * 72 + (o1 & 63)) = kr1;
                *(uint4*)(Vs + ve * 72 + vc)     = vr0;
                *(uint4*)(Vs + ve * 72 + vc + 8) = vr1;
            }
            __syncthreads();

            if (kt + 2 < 32) {
                const int j2 = (kt + 2) * 64;
                kr0 = *(const uint4*)(D + j2 * 64 + t * 8);
                kr1 = *(const uint4*)(D + j2 * 64 + 2048 + t * 8);
                vr0 = *(const uint4*)(VT + (size_t)ve * SEQ + j2 + vc);
                vr1 = *(const uint4*)(VT + (size_t)ve * SEQ + j2 + vc + 8);
            }

            f32x4 s[4] = {};
#pragma unroll
            for (int kh = 0; kh < 2; kh++)
#pragma unroll
                for (int nt = 0; nt < 4; nt++) {
                    f16x8 bfr = *(const f16x8*)(Ks + (nt * 16 + ln) * 72 + kh * 32 + quad * 8);
                    s[nt] = __builtin_amdgcn_mfma_f32_16x16x32_f16(aq[kh], bfr, s[nt], 0, 0, 0);
                }

            const bool full = (kt > qt);
#pragma unroll
            for (int nt = 0; nt < 4; nt++)
#pragma unroll
                for (int r = 0; r < 4; r++) {
                    const int iloc = w * 16 + quad * 4 + r;
                    const int jloc = nt * 16 + ln;
                    float p = (full || (jloc > iloc))
                                  ? fminf(__expf(fmaf(s[nt][r], -0.5f,
                                                      -11.090354888959125f)), 60000.0f)
                                  : 0.0f;
                    Ps[iloc * 72 + jloc] = (f16)p;
                }

#pragma unroll
            for (int kh = 0; kh < 2; kh++) {
                f16x8 a = *(const f16x8*)(Ps + (w * 16 + ln) * 72 + kh * 32 + quad * 8);
#pragma unroll
                for (int nt = 0; nt < 4; nt++) {
                    f16x8 bfr = *(const f16x8*)(Vs + (nt * 16 + ln) * 72 + kh * 32 + quad * 8);
                    acc[nt] = __builtin_amdgcn_mfma_f32_16x16x32_f16(a, bfr, acc[nt], 0, 0, 0);
                }
            }
        }

#pragma unroll
        for (int nt = 0; nt < 4; nt++)
#pragma unroll
            for (int r = 0; r < 4; r++) {
                const int iloc = w * 16 + quad * 4 + r;
                Cout[(size_t)(b * SEQ + i0 + iloc) * HID + h * 64 + nt * 16 + ln] =
                    (f16)acc[nt][r];
            }
    }
}

// ---------------------------------------------------------------------------
extern "C" void kernel_launch(void* const* d_in, const int* in_sizes, int n_in,
                              void* d_out, int out_size, void* d_ws, size_t ws_size,
                              hipStream_t stream) {
    const float* x  = (const float*)d_in[0];
    const float* Wq = (const float*)d_in[1];
    const float* bq = (const float*)d_in[2];
    const float* Wk = (const float*)d_in[3];
    const float* bk = (const float*)d_in[4];
    const float* Wv = (const float*)d_in[5];
    const float* bv = (const float*)d_in[6];
    const float* Wo = (const float*)d_in[7];
    const float* bo = (const float*)d_in[8];
    float* out = (float*)d_out;

    char* ws = (char*)d_ws;
    f16* xh   = (f16*)(ws);               // 8 MB  [M][1024]
    f16* WqkT = (f16*)(ws + (8 << 20));   // 2 MB  [n][k]
    f16* WvT  = (f16*)(ws + (10 << 20));  // 2 MB
    f16* WoT  = (f16*)(ws + (12 << 20));  // 2 MB
    f16* dif  = (f16*)(ws + (14 << 20));  // 8 MB  [bh][s][64]
    f16* vT   = (f16*)(ws + (22 << 20));  // 8 MB  [bh][e][s]
    f16* ctx0 = (f16*)(ws + (30 << 20));  // 8 MB  partial (x 2^-16)
    f16* ctx1 = (f16*)(ws + (38 << 20));  // 8 MB  partial

    prep<<<dim3(16, 16, 4), 256, 0, stream>>>(x, Wq, Wk, Wv, Wo,
                                              xh, WqkT, WvT, WoT);
    proj_gemm<<<dim3(MTOT / 128, 32), 256, 0, stream>>>(xh, WqkT, WvT,
                                                        bq, bk, bv, dif, vT);
    attn_f16<<<dim3(16, BH, 2), 256, 0, stream>>>(dif, vT, ctx0, ctx1);
    out_gemm<<<dim3(MTOT / 128, 16), 256, 0, stream>>>(ctx0, ctx1, WoT, bo, out);
}